// Round 6
// baseline (969.127 us; speedup 1.0000x reference)
//
#include <hip/hip_runtime.h>

#define LRELU(v) ((v) > 0.f ? (v) : 0.2f * (v))

// ---------------------------------------------------------------------------
// DPP-based full-wave (64 lane) sum.  VALU only, no DS traffic.
template <int CTRL, int RMASK>
__device__ __forceinline__ float dpp_add(float v) {
  int moved = __builtin_amdgcn_update_dpp(0, __builtin_bit_cast(int, v), CTRL,
                                          RMASK, 0xf, true);
  return v + __builtin_bit_cast(float, moved);
}
__device__ __forceinline__ float wave_sum(float v) {
  v = dpp_add<0x111, 0xf>(v);  // row_shr:1
  v = dpp_add<0x112, 0xf>(v);  // row_shr:2
  v = dpp_add<0x114, 0xf>(v);  // row_shr:4
  v = dpp_add<0x118, 0xf>(v);  // row_shr:8
  v = dpp_add<0x142, 0xa>(v);  // row_bcast:15
  v = dpp_add<0x143, 0xc>(v);  // row_bcast:31; lane63 = total
  return __builtin_bit_cast(
      float, __builtin_amdgcn_readlane(__builtin_bit_cast(int, v), 63));
}

// ---------------------------------------------------------------------------
// Both embeddings in one dispatch: lrelu(X[M,K] @ W[K,64] + b) -> out[M,64].
__global__ __launch_bounds__(256) void embed2_kernel(
    const float* __restrict__ x, const float* __restrict__ nW,
    const float* __restrict__ nb, float* __restrict__ h0, int N_,
    const float* __restrict__ eattr, const float* __restrict__ eW,
    const float* __restrict__ eb, float* __restrict__ ea, int E_,
    int nodeBlocks) {
  const int lane = threadIdx.x & 63;
  const float *X, *W, *b;
  float* out;
  int M, K, r;
  if ((int)blockIdx.x < nodeBlocks) {
    r = blockIdx.x * 4 + (threadIdx.x >> 6);
    X = x; W = nW; b = nb; out = h0; M = N_; K = 92;
  } else {
    r = (blockIdx.x - nodeBlocks) * 4 + (threadIdx.x >> 6);
    X = eattr; W = eW; b = eb; out = ea; M = E_; K = 50;
  }
  r = __builtin_amdgcn_readfirstlane(r);
  if (r >= M) return;
  float acc = b[lane];
  const float* Xr = X + (size_t)r * K;
  const float* Wl = W + lane;
  for (int k = 0; k < K; ++k) acc = fmaf(Xr[k], Wl[(size_t)k * 64], acc);
  acc = LRELU(acc);
  out[(size_t)r * 64 + lane] = acc;
}

// ---------------------------------------------------------------------------
// eaT[c][e] = ea[e][c]: 64x64 LDS-tiled transpose so the edge kernel can
// fetch 8 consecutive edges' ea values with one s_load_dwordx8.
__global__ __launch_bounds__(256) void transpose_kernel(
    const float* __restrict__ ea, float* __restrict__ eaT, int E_) {
  __shared__ float tile[64][65];
  int e0 = blockIdx.x * 64;
  int c = threadIdx.x & 63, rr = threadIdx.x >> 6;
#pragma unroll
  for (int i = 0; i < 16; ++i) {
    int r = rr + i * 4;
    if (e0 + r < E_) tile[r][c] = ea[(size_t)(e0 + r) * 64 + c];
  }
  __syncthreads();
#pragma unroll
  for (int i = 0; i < 16; ++i) {
    int cc = rr + i * 4;
    if (e0 + c < E_) eaT[(size_t)cc * E_ + e0 + c] = tile[c][cc];
  }
}

// ---------------------------------------------------------------------------
// Fused finalize(prev layer) + P = h @ W_top  (R4-proven form).
// mode -1: A = A0 (layer 0); mode 0: h = agg*0.1+b; mode 1: h += agg*0.1+b.
__global__ __launch_bounds__(256, 4) void update_gemm_kernel(
    const float* __restrict__ A0, float* __restrict__ h,
    float* __restrict__ agg, const float* __restrict__ bvec,
    const float* __restrict__ W, float* __restrict__ P, int M, int mode) {
  const int lane = threadIdx.x & 63;
  const int wv =
      __builtin_amdgcn_readfirstlane(blockIdx.x * 4 + (threadIdx.x >> 6));
  const int r0 = wv * 4;
  if (r0 >= M) return;
  float hv[4];
  if (mode < 0) {
#pragma unroll
    for (int r = 0; r < 4; ++r) hv[r] = A0[(size_t)(r0 + r) * 64 + lane];
  } else {
    float bl = bvec[lane];
#pragma unroll
    for (int r = 0; r < 4; ++r) {
      size_t idx = (size_t)(r0 + r) * 64 + lane;
      float v = fmaf(agg[idx], 0.1f, bl);
      if (mode >= 1) v += h[idx];
      agg[idx] = 0.f;
      h[idx] = v;
      hv[r] = v;
    }
  }
  float acc[4][10];
#pragma unroll
  for (int r = 0; r < 4; ++r)
#pragma unroll
    for (int q = 0; q < 10; ++q) acc[r][q] = 0.f;
  const float* Wl = W + lane;
  float wa[10], wb[10];
#pragma unroll
  for (int q = 0; q < 10; ++q) wa[q] = Wl[q * 64];
#pragma unroll 1
  for (int k = 0; k < 64; k += 2) {
#pragma unroll
    for (int q = 0; q < 10; ++q) wb[q] = Wl[(k + 1) * 640 + q * 64];
#pragma unroll
    for (int r = 0; r < 4; ++r) {
      float a = __shfl(hv[r], k);
#pragma unroll
      for (int q = 0; q < 10; ++q) acc[r][q] = fmaf(a, wa[q], acc[r][q]);
    }
    if (k + 2 < 64) {
#pragma unroll
      for (int q = 0; q < 10; ++q) wa[q] = Wl[(k + 2) * 640 + q * 64];
    }
#pragma unroll
    for (int r = 0; r < 4; ++r) {
      float a = __shfl(hv[r], k + 1);
#pragma unroll
      for (int q = 0; q < 10; ++q) acc[r][q] = fmaf(a, wb[q], acc[r][q]);
    }
  }
#pragma unroll
  for (int r = 0; r < 4; ++r) {
    float* Crow = P + (size_t)(r0 + r) * 640;
#pragma unroll
    for (int q = 0; q < 10; ++q) Crow[q * 64 + lane] = acc[r][q];
  }
}

// ---------------------------------------------------------------------------
// Edge kernel, head-online version.  8 edges/wave, ONE head at a time:
//   per head: qa[8] k-loop (ea via s_load_dwordx8 from eaT, W dword dbuf),
//   wave_sum logit, groupnorm, then ONLINE softmax-over-heads update of the
//   per-edge message m[8] (rescale by exp(mx_old-mx_new)).
// Peak live VGPRs ~55 (qa8+pr8+pc8+m8+mx/ss+misc) -> no allocator fission.
__global__ __launch_bounds__(256, 4) void edge_fused_kernel(
    const float* __restrict__ P, const float* __restrict__ eaT,  // [64][E]
    const float* __restrict__ Wbot,  // [64][640]
    const int* __restrict__ row, const int* __restrict__ col,
    const float* __restrict__ att, const float* __restrict__ gamma,
    const float* __restrict__ beta, float* __restrict__ agg, int E_) {
  const int lane = threadIdx.x & 63;
  const int wv =
      __builtin_amdgcn_readfirstlane(blockIdx.x * 4 + (threadIdx.x >> 6));
  const int e0 = wv * 8;
  if (e0 >= E_) return;

  int ris[8], cis[8];
#pragma unroll
  for (int r = 0; r < 8; ++r) {
    int e = (e0 + r < E_) ? (e0 + r) : (E_ - 1);
    ris[r] = row[e];
    cis[r] = col[e];
  }

  const float inv_std = 0.9999950000374997f;  // 1/sqrt(1+1e-5)
  float m[8], mx[8], ss[8];
#pragma unroll
  for (int r = 0; r < 8; ++r) {
    m[r] = 0.f;
    mx[r] = -1e30f;
    ss[r] = 0.f;
  }

  const float* Wl = Wbot + lane;
#pragma unroll 1
  for (int h = 0; h < 10; ++h) {
    // P gathers for this head issued first; the k-loop hides their latency.
    float pr[8], pc[8];
#pragma unroll
    for (int r = 0; r < 8; ++r) {
      pr[r] = P[(size_t)ris[r] * 640 + h * 64 + lane];
      pc[r] = P[(size_t)cis[r] * 640 + h * 64 + lane];
    }
    float at_i = att[h * 128 + lane];
    float at_j = att[h * 128 + 64 + lane];
    float gm = gamma[h], bt = beta[h];

    float qa[8];
#pragma unroll
    for (int r = 0; r < 8; ++r) qa[r] = 0.f;
    const float* Wh = Wl + h * 64;
    float wa = Wh[0];
#pragma unroll 1
    for (int k = 0; k < 64; k += 2) {
      float wb = Wh[(size_t)(k + 1) * 640];
      const float* s0 = eaT + (size_t)k * E_ + e0;       // uniform -> s_load
      const float* s1 = eaT + (size_t)(k + 1) * E_ + e0;
#pragma unroll
      for (int r = 0; r < 8; ++r) qa[r] = fmaf(s0[r], wa, qa[r]);
      if (k + 2 < 64) wa = Wh[(size_t)(k + 2) * 640];
#pragma unroll
      for (int r = 0; r < 8; ++r) qa[r] = fmaf(s1[r], wb, qa[r]);
    }

#pragma unroll
    for (int r = 0; r < 8; ++r) {
      if (e0 + r < E_) {
        float hi = pr[r] + qa[r];
        float hjv = pc[r] + qa[r];
        hi = LRELU(hi);
        hjv = LRELU(hjv);
        float part = fmaf(hi, at_i, hjv * at_j);
        float s = wave_sum(part);  // uniform
        float a = LRELU(s);
        a = fmaf(a * inv_std, gm, bt);
        float nm = fmaxf(mx[r], a);
        float scale = __expf(mx[r] - nm);  // 0 on first head
        float ex = __expf(a - nm);
        ss[r] = fmaf(ss[r], scale, ex);
        m[r] = fmaf(m[r], scale, ex * hjv);
        mx[r] = nm;
      }
    }
  }

#pragma unroll
  for (int r = 0; r < 8; ++r) {
    if (e0 + r >= E_) break;
    float inv = 1.0f / ss[r];
    atomicAdd(agg + (size_t)ris[r] * 64 + lane, m[r] * inv);
  }
}

// ---------------------------------------------------------------------------
// Final residual: h = h + agg/NH + b + h0.  Also re-zeroes agg.
__global__ __launch_bounds__(256) void finalize_kernel(
    float* __restrict__ h, float* __restrict__ agg, const float* __restrict__ b,
    const float* __restrict__ h0, int total) {
  int idx = blockIdx.x * 256 + threadIdx.x;
  if (idx >= total) return;
  int f = idx & 63;
  float v = fmaf(agg[idx], 0.1f, b[f]);
  agg[idx] = 0.f;
  h[idx] = v + h[idx] + h0[idx];
}

// ---------------------------------------------------------------------------
// score[n] = lrelu([h[n], gf[batch[n]]] @ W1 + b1) @ W2 + b2.  Wave per node.
__global__ __launch_bounds__(256) void score_kernel(
    const float* __restrict__ h, const int* __restrict__ batch,
    const float* __restrict__ gf, const float* __restrict__ W1,
    const float* __restrict__ b1, const float* __restrict__ W2,
    const float* __restrict__ b2, float* __restrict__ score, int N_) {
  const int lane = threadIdx.x & 63;
  const int n =
      __builtin_amdgcn_readfirstlane(blockIdx.x * 4 + (threadIdx.x >> 6));
  if (n >= N_) return;
  float acc = b1[lane];
  const float* hn = h + (size_t)n * 64;  // uniform -> s_load
  const float* W1l = W1 + lane;
#pragma unroll 8
  for (int k = 0; k < 64; ++k) acc = fmaf(hn[k], W1l[k * 64], acc);
  const int bn = batch[n];  // scalar
  const float* g = gf + (size_t)bn * 108;
#pragma unroll 4
  for (int k = 0; k < 108; ++k) acc = fmaf(g[k], W1l[(64 + k) * 64], acc);
  acc = LRELU(acc);
  float v = wave_sum(acc * W2[lane]);
  if (lane == 0) score[n] = v + b2[0];
}

// ---------------------------------------------------------------------------
// Graph boundary offsets from sorted batch_idx: start[g]..start[g+1]
__global__ void bounds_kernel(const int* __restrict__ batch,
                              int* __restrict__ start, int N_, int G_) {
  int n = blockIdx.x * blockDim.x + threadIdx.x;
  if (n >= N_) return;
  int b = batch[n];
  int bp = (n == 0) ? -1 : batch[n - 1];
  for (int g = bp + 1; g <= b; ++g) start[g] = n;
  if (n == N_ - 1)
    for (int g = b + 1; g <= G_; ++g) start[g] = N_;
}

// ---------------------------------------------------------------------------
// Per-graph softmax-attention pool + output MLP.  One block per graph.
__global__ __launch_bounds__(256) void pool_out_kernel(
    const float* __restrict__ h, const float* __restrict__ score,
    const int* __restrict__ start, const float* __restrict__ W1,
    const float* __restrict__ b1, const float* __restrict__ W2,
    const float* __restrict__ b2, float* __restrict__ out) {
  int g = blockIdx.x;
  int s0 = start[g], s1 = start[g + 1];
  int tid = threadIdx.x;
  __shared__ float red[256];
  __shared__ float pool[64];
  __shared__ float sh_smax, sh_denom;
  float lm = -1e30f;
  for (int n = s0 + tid; n < s1; n += 256) lm = fmaxf(lm, score[n]);
  red[tid] = lm;
  __syncthreads();
  for (int off = 128; off; off >>= 1) {
    if (tid < off) red[tid] = fmaxf(red[tid], red[tid + off]);
    __syncthreads();
  }
  if (tid == 0) sh_smax = red[0];
  __syncthreads();
  float smax = sh_smax;
  __syncthreads();
  float ls = 0.f;
  for (int n = s0 + tid; n < s1; n += 256) ls += __expf(score[n] - smax);
  red[tid] = ls;
  __syncthreads();
  for (int off = 128; off; off >>= 1) {
    if (tid < off) red[tid] += red[tid + off];
    __syncthreads();
  }
  if (tid == 0) sh_denom = red[0];
  __syncthreads();
  float denom = sh_denom;
  float invd = denom > 0.f ? 1.0f / denom : 0.f;
  __syncthreads();
  int f = tid & 63, sub = tid >> 6;
  float acc = 0.f;
  for (int n = s0 + sub; n < s1; n += 4)
    acc = fmaf(__expf(score[n] - smax), h[(size_t)n * 64 + f], acc);
  red[tid] = acc;
  __syncthreads();
  if (tid < 64)
    pool[tid] =
        (red[tid] + red[tid + 64] + red[tid + 128] + red[tid + 192]) * invd;
  __syncthreads();
  if (tid < 64) {
    float a = b1[tid];
#pragma unroll 8
    for (int k = 0; k < 64; ++k) a = fmaf(pool[k], W1[k * 64 + tid], a);
    a = fmaxf(a, 0.f);
    red[tid] = a * W2[tid];
  }
  __syncthreads();
  if (tid == 0) {
    float s = 0.f;
    for (int k = 0; k < 64; ++k) s += red[k];
    out[g] = s + b2[0];
  }
}

// ---------------------------------------------------------------------------
extern "C" void kernel_launch(void* const* d_in, const int* in_sizes, int n_in,
                              void* d_out, int out_size, void* d_ws,
                              size_t ws_size, hipStream_t stream) {
  const float* x          = (const float*)d_in[0];
  const int*   edge_index = (const int*)d_in[1];
  const float* edge_attr  = (const float*)d_in[2];
  const int*   batch_idx  = (const int*)d_in[3];
  const float* gf         = (const float*)d_in[4];
  const float* node_W     = (const float*)d_in[5];
  const float* node_b     = (const float*)d_in[6];
  const float* edge_W     = (const float*)d_in[7];
  const float* edge_b     = (const float*)d_in[8];
  const float* conv_W     = (const float*)d_in[9];
  const float* conv_att   = (const float*)d_in[10];
  const float* conv_b     = (const float*)d_in[11];
  const float* conv_gamma = (const float*)d_in[12];
  const float* conv_beta  = (const float*)d_in[13];
  const float* ga_W1      = (const float*)d_in[14];
  const float* ga_b1      = (const float*)d_in[15];
  const float* ga_W2      = (const float*)d_in[16];
  const float* ga_b2      = (const float*)d_in[17];
  const float* out_W1     = (const float*)d_in[18];
  const float* out_b1     = (const float*)d_in[19];
  const float* out_W2     = (const float*)d_in[20];
  const float* out_b2     = (const float*)d_in[21];
  float* out = (float*)d_out;

  const int N = in_sizes[3];        // 10000
  const int E = in_sizes[2] / 50;   // 40000
  const int G = in_sizes[4] / 108;  // 128
  const int L = 5;

  float* ws = (float*)d_ws;
  float* h    = ws;  ws += (size_t)N * 64;
  float* h0   = ws;  ws += (size_t)N * 64;
  float* ea   = ws;  ws += (size_t)E * 64;
  float* eaT  = ws;  ws += (size_t)E * 64 + 16;  // +pad for tail s_loads
  float* P    = ws;  ws += (size_t)N * 640;
  float* agg  = ws;  ws += (size_t)N * 64;
  float* scr  = ws;  ws += N;
  int* gstart = (int*)ws;

  const int* row = edge_index;
  const int* col = edge_index + E;

  int nodeBlocks = (N + 3) / 4;
  int edgeBlocks = (E + 3) / 4;
  embed2_kernel<<<nodeBlocks + edgeBlocks, 256, 0, stream>>>(
      x, node_W, node_b, h0, N, edge_attr, edge_W, edge_b, ea, E, nodeBlocks);
  transpose_kernel<<<(E + 63) / 64, 256, 0, stream>>>(ea, eaT, E);
  (void)hipMemsetAsync(agg, 0, (size_t)N * 64 * sizeof(float), stream);

  for (int i = 0; i < L; ++i) {
    const float* Wi = conv_W + (size_t)i * 128 * 640;
    if (i == 0) {
      update_gemm_kernel<<<(N / 4 + 3) / 4, 256, 0, stream>>>(
          h0, h, agg, nullptr, Wi, P, N, -1);
    } else {
      update_gemm_kernel<<<(N / 4 + 3) / 4, 256, 0, stream>>>(
          nullptr, h, agg, conv_b + (i - 1) * 64, Wi, P, N,
          (i - 1) == 0 ? 0 : 1);
    }
    int waves = (E + 7) / 8;
    edge_fused_kernel<<<(waves + 3) / 4, 256, 0, stream>>>(
        P, eaT, Wi + 64 * 640, row, col, conv_att + (size_t)i * 1280,
        conv_gamma + i * 10, conv_beta + i * 10, agg, E);
  }
  finalize_kernel<<<(N * 64 + 255) / 256, 256, 0, stream>>>(
      h, agg, conv_b + (L - 1) * 64, h0, N * 64);

  score_kernel<<<(N + 3) / 4, 256, 0, stream>>>(h, batch_idx, gf, ga_W1, ga_b1,
                                                ga_W2, ga_b2, scr, N);
  bounds_kernel<<<(N + 255) / 256, 256, 0, stream>>>(batch_idx, gstart, N, G);
  pool_out_kernel<<<G, 256, 0, stream>>>(h, scr, gstart, out_W1, out_b1, out_W2,
                                         out_b2, out);
}

// Round 7
// 728.372 us; speedup vs baseline: 1.3305x; 1.3305x over previous
//
#include <hip/hip_runtime.h>

#define LRELU(v) ((v) > 0.f ? (v) : 0.2f * (v))

// ---------------------------------------------------------------------------
// DPP-based full-wave (64 lane) sum.  VALU only, no DS traffic.
template <int CTRL, int RMASK>
__device__ __forceinline__ float dpp_add(float v) {
  int moved = __builtin_amdgcn_update_dpp(0, __builtin_bit_cast(int, v), CTRL,
                                          RMASK, 0xf, true);
  return v + __builtin_bit_cast(float, moved);
}
__device__ __forceinline__ float wave_sum(float v) {
  v = dpp_add<0x111, 0xf>(v);  // row_shr:1
  v = dpp_add<0x112, 0xf>(v);  // row_shr:2
  v = dpp_add<0x114, 0xf>(v);  // row_shr:4
  v = dpp_add<0x118, 0xf>(v);  // row_shr:8
  v = dpp_add<0x142, 0xa>(v);  // row_bcast:15
  v = dpp_add<0x143, 0xc>(v);  // row_bcast:31; lane63 = total
  return __builtin_bit_cast(
      float, __builtin_amdgcn_readlane(__builtin_bit_cast(int, v), 63));
}

// ---------------------------------------------------------------------------
// Both embeddings in one dispatch: lrelu(X[M,K] @ W[K,64] + b) -> out[M,64].
__global__ __launch_bounds__(256) void embed2_kernel(
    const float* __restrict__ x, const float* __restrict__ nW,
    const float* __restrict__ nb, float* __restrict__ h0, int N_,
    const float* __restrict__ eattr, const float* __restrict__ eW,
    const float* __restrict__ eb, float* __restrict__ ea, int E_,
    int nodeBlocks) {
  const int lane = threadIdx.x & 63;
  const float *X, *W, *b;
  float* out;
  int M, K, r;
  if ((int)blockIdx.x < nodeBlocks) {
    r = blockIdx.x * 4 + (threadIdx.x >> 6);
    X = x; W = nW; b = nb; out = h0; M = N_; K = 92;
  } else {
    r = (blockIdx.x - nodeBlocks) * 4 + (threadIdx.x >> 6);
    X = eattr; W = eW; b = eb; out = ea; M = E_; K = 50;
  }
  r = __builtin_amdgcn_readfirstlane(r);
  if (r >= M) return;
  float acc = b[lane];
  const float* Xr = X + (size_t)r * K;
  const float* Wl = W + lane;
  for (int k = 0; k < K; ++k) acc = fmaf(Xr[k], Wl[(size_t)k * 64], acc);
  acc = LRELU(acc);
  out[(size_t)r * 64 + lane] = acc;
}

// ---------------------------------------------------------------------------
// Edge counting-sort by row (reused by all 5 layers).
__global__ __launch_bounds__(256) void count_kernel(const int* __restrict__ row,
                                                    int* __restrict__ cnt,
                                                    int E_) {
  int e = blockIdx.x * 256 + threadIdx.x;
  if (e < E_) atomicAdd(&cnt[row[e]], 1);
}

// Single-block exclusive scan of cnt[N] -> cursor[N] (start offsets).
__global__ __launch_bounds__(256) void scan_kernel(const int* __restrict__ cnt,
                                                   int* __restrict__ cursor,
                                                   int N_) {
  __shared__ int part[256];
  int t = threadIdx.x;
  int per = (N_ + 255) / 256;
  int lo = t * per, hi = min(N_, lo + per);
  int s = 0;
  for (int i = lo; i < hi; ++i) s += cnt[i];
  part[t] = s;
  __syncthreads();
  for (int off = 1; off < 256; off <<= 1) {
    int v = (t >= off) ? part[t - off] : 0;
    __syncthreads();
    part[t] += v;
    __syncthreads();
  }
  int excl = (t == 0) ? 0 : part[t - 1];
  for (int i = lo; i < hi; ++i) {
    cursor[i] = excl;
    excl += cnt[i];
  }
}

// Scatter edges to sorted-by-row positions.  cursor is consumed.
__global__ __launch_bounds__(256) void scatter_kernel(
    const int* __restrict__ row, const int* __restrict__ col,
    int* __restrict__ cursor, int* __restrict__ rs, int* __restrict__ cs,
    int* __restrict__ es, int E_) {
  int e = blockIdx.x * 256 + threadIdx.x;
  if (e >= E_) return;
  int r = row[e];
  int p = atomicAdd(&cursor[r], 1);
  rs[p] = r;
  cs[p] = col[e];
  es[p] = e;
}

// Permute ea rows into sorted order so edge-kernel scalar loads stay
// contiguous: eas[p][c] = ea[es[p]][c].
__global__ __launch_bounds__(256) void gather_ea_kernel(
    const float* __restrict__ ea, const int* __restrict__ es,
    float* __restrict__ eas, int E_) {
  int idx = blockIdx.x * 256 + threadIdx.x;
  if (idx >= E_ * 64) return;
  int p = idx >> 6, c = idx & 63;
  eas[idx] = ea[(size_t)es[p] * 64 + c];
}

// ---------------------------------------------------------------------------
// Fused finalize(prev layer) + P = h @ W_top  (R4-proven form).
// mode -1: A = A0 (layer 0); mode 0: h = agg*0.1+b; mode 1: h += agg*0.1+b.
__global__ __launch_bounds__(256, 4) void update_gemm_kernel(
    const float* __restrict__ A0, float* __restrict__ h,
    float* __restrict__ agg, const float* __restrict__ bvec,
    const float* __restrict__ W, float* __restrict__ P, int M, int mode) {
  const int lane = threadIdx.x & 63;
  const int wv =
      __builtin_amdgcn_readfirstlane(blockIdx.x * 4 + (threadIdx.x >> 6));
  const int r0 = wv * 4;
  if (r0 >= M) return;
  float hv[4];
  if (mode < 0) {
#pragma unroll
    for (int r = 0; r < 4; ++r) hv[r] = A0[(size_t)(r0 + r) * 64 + lane];
  } else {
    float bl = bvec[lane];
#pragma unroll
    for (int r = 0; r < 4; ++r) {
      size_t idx = (size_t)(r0 + r) * 64 + lane;
      float v = fmaf(agg[idx], 0.1f, bl);
      if (mode >= 1) v += h[idx];
      agg[idx] = 0.f;
      h[idx] = v;
      hv[r] = v;
    }
  }
  float acc[4][10];
#pragma unroll
  for (int r = 0; r < 4; ++r)
#pragma unroll
    for (int q = 0; q < 10; ++q) acc[r][q] = 0.f;
  const float* Wl = W + lane;
  float wa[10], wb[10];
#pragma unroll
  for (int q = 0; q < 10; ++q) wa[q] = Wl[q * 64];
#pragma unroll 1
  for (int k = 0; k < 64; k += 2) {
#pragma unroll
    for (int q = 0; q < 10; ++q) wb[q] = Wl[(k + 1) * 640 + q * 64];
#pragma unroll
    for (int r = 0; r < 4; ++r) {
      float a = __shfl(hv[r], k);
#pragma unroll
      for (int q = 0; q < 10; ++q) acc[r][q] = fmaf(a, wa[q], acc[r][q]);
    }
    if (k + 2 < 64) {
#pragma unroll
      for (int q = 0; q < 10; ++q) wa[q] = Wl[(k + 2) * 640 + q * 64];
    }
#pragma unroll
    for (int r = 0; r < 4; ++r) {
      float a = __shfl(hv[r], k + 1);
#pragma unroll
      for (int q = 0; q < 10; ++q) acc[r][q] = fmaf(a, wb[q], acc[r][q]);
    }
  }
#pragma unroll
  for (int r = 0; r < 4; ++r) {
    float* Crow = P + (size_t)(r0 + r) * 640;
#pragma unroll
    for (int q = 0; q < 10; ++q) Crow[q * 64 + lane] = acc[r][q];
  }
}

// ---------------------------------------------------------------------------
// R4-proven edge kernel operating on ROW-SORTED edges:
//  - eas is the sorted ea (contiguous rows -> uniform s_load per k);
//  - rs sorted => the 8 edges/wave share ~2-3 distinct rows: pr gathers hit
//    L1 after the first edge, and agg atomics merge in-register per run.
__global__ __launch_bounds__(256, 3) void edge_fused_kernel(
    const float* __restrict__ P, const float* __restrict__ eas,
    const float* __restrict__ Wbot,  // [64, 640]
    const int* __restrict__ rs, const int* __restrict__ cs,
    const float* __restrict__ att, const float* __restrict__ gamma,
    const float* __restrict__ beta, float* __restrict__ agg, int E_) {
  const int lane = threadIdx.x & 63;
  const int wv =
      __builtin_amdgcn_readfirstlane(blockIdx.x * 4 + (threadIdx.x >> 6));
  const int e0 = wv * 8;
  if (e0 >= E_) return;

  int ris[8], cis[8];
#pragma unroll
  for (int r = 0; r < 8; ++r) {
    int e = (e0 + r < E_) ? (e0 + r) : (E_ - 1);
    ris[r] = rs[e];
    cis[r] = cs[e];
  }

  float qacc[8][10];
#pragma unroll
  for (int r = 0; r < 8; ++r)
#pragma unroll
    for (int q = 0; q < 10; ++q) qacc[r][q] = 0.f;

  const float* eaw = eas + (size_t)e0 * 64;  // uniform base -> s_load
  const float* Wl = Wbot + lane;
  float wa[10], wb[10];
#pragma unroll
  for (int q = 0; q < 10; ++q) wa[q] = Wl[q * 64];
#pragma unroll 1
  for (int k = 0; k < 64; k += 2) {
#pragma unroll
    for (int q = 0; q < 10; ++q) wb[q] = Wl[(k + 1) * 640 + q * 64];
#pragma unroll
    for (int r = 0; r < 8; ++r) {
      float a = eaw[r * 64 + k];  // wave-uniform scalar load
#pragma unroll
      for (int q = 0; q < 10; ++q) qacc[r][q] = fmaf(a, wa[q], qacc[r][q]);
    }
    if (k + 2 < 64) {
#pragma unroll
      for (int q = 0; q < 10; ++q) wa[q] = Wl[(k + 2) * 640 + q * 64];
    }
#pragma unroll
    for (int r = 0; r < 8; ++r) {
      float a = eaw[r * 64 + k + 1];
#pragma unroll
      for (int q = 0; q < 10; ++q) qacc[r][q] = fmaf(a, wb[q], qacc[r][q]);
    }
  }

  const float inv_std = 0.9999950000374997f;  // 1/sqrt(1+1e-5)
  float gm[10], bt[10];  // wave-uniform -> SGPRs
#pragma unroll
  for (int q = 0; q < 10; ++q) {
    gm[q] = gamma[q];
    bt[q] = beta[q];
  }

  // Prefetch edge 0's P rows.
  float prb[10], pcb[10];
  {
    const float* Pr = P + (size_t)ris[0] * 640 + lane;
    const float* Pc = P + (size_t)cis[0] * 640 + lane;
#pragma unroll
    for (int q = 0; q < 10; ++q) {
      prb[q] = Pr[q * 64];
      pcb[q] = Pc[q * 64];
    }
  }

  float pend = 0.f;   // pending merged atomic value for current row run
  int prow = ris[0];  // current run's row

#pragma unroll
  for (int r = 0; r < 8; ++r) {
    if (e0 + r >= E_) break;
    float pr[10], pc[10];
#pragma unroll
    for (int q = 0; q < 10; ++q) {
      pr[q] = prb[q];
      pc[q] = pcb[q];
    }
    if (r + 1 < 8) {  // issue next edge's gathers now
      const float* Pr = P + (size_t)ris[r + 1] * 640 + lane;
      const float* Pc = P + (size_t)cis[r + 1] * 640 + lane;
#pragma unroll
      for (int q = 0; q < 10; ++q) {
        prb[q] = Pr[q * 64];
        pcb[q] = Pc[q * 64];
      }
    }
    float hj[10], sv[10];
#pragma unroll
    for (int q = 0; q < 10; ++q) {
      float qc = qacc[r][q];
      float hi = pr[q] + qc;
      float hjv = pc[q] + qc;
      hi = LRELU(hi);
      hjv = LRELU(hjv);
      hj[q] = hjv;
      float part =
          fmaf(hi, att[q * 128 + lane], hjv * att[q * 128 + 64 + lane]);
      sv[q] = wave_sum(part);  // uniform after this
    }
    float mx = -1e30f;
#pragma unroll
    for (int q = 0; q < 10; ++q) {
      float a = sv[q];
      a = LRELU(a);
      a = fmaf(a * inv_std, gm[q], bt[q]);
      sv[q] = a;
      mx = fmaxf(mx, a);
    }
    float ssum = 0.f;
#pragma unroll
    for (int q = 0; q < 10; ++q) {
      float ex = __expf(sv[q] - mx);
      sv[q] = ex;
      ssum += ex;
    }
    float inv = 1.0f / ssum;
    float m = 0.f;
#pragma unroll
    for (int q = 0; q < 10; ++q) m = fmaf(sv[q] * inv, hj[q], m);
    // Merge atomics across the sorted row run.
    if (ris[r] != prow) {
      atomicAdd(agg + (size_t)prow * 64 + lane, pend);
      pend = 0.f;
      prow = ris[r];
    }
    pend += m;
  }
  atomicAdd(agg + (size_t)prow * 64 + lane, pend);
}

// ---------------------------------------------------------------------------
// Final residual: h = h + agg/NH + b + h0.  Also re-zeroes agg.
__global__ __launch_bounds__(256) void finalize_kernel(
    float* __restrict__ h, float* __restrict__ agg, const float* __restrict__ b,
    const float* __restrict__ h0, int total) {
  int idx = blockIdx.x * 256 + threadIdx.x;
  if (idx >= total) return;
  int f = idx & 63;
  float v = fmaf(agg[idx], 0.1f, b[f]);
  agg[idx] = 0.f;
  h[idx] = v + h[idx] + h0[idx];
}

// ---------------------------------------------------------------------------
// score[n] = lrelu([h[n], gf[batch[n]]] @ W1 + b1) @ W2 + b2.  Wave per node.
__global__ __launch_bounds__(256) void score_kernel(
    const float* __restrict__ h, const int* __restrict__ batch,
    const float* __restrict__ gf, const float* __restrict__ W1,
    const float* __restrict__ b1, const float* __restrict__ W2,
    const float* __restrict__ b2, float* __restrict__ score, int N_) {
  const int lane = threadIdx.x & 63;
  const int n =
      __builtin_amdgcn_readfirstlane(blockIdx.x * 4 + (threadIdx.x >> 6));
  if (n >= N_) return;
  float acc = b1[lane];
  const float* hn = h + (size_t)n * 64;  // uniform -> s_load
  const float* W1l = W1 + lane;
#pragma unroll 8
  for (int k = 0; k < 64; ++k) acc = fmaf(hn[k], W1l[k * 64], acc);
  const int bn = batch[n];  // scalar
  const float* g = gf + (size_t)bn * 108;
#pragma unroll 4
  for (int k = 0; k < 108; ++k) acc = fmaf(g[k], W1l[(64 + k) * 64], acc);
  acc = LRELU(acc);
  float v = wave_sum(acc * W2[lane]);
  if (lane == 0) score[n] = v + b2[0];
}

// ---------------------------------------------------------------------------
// Graph boundary offsets from sorted batch_idx: start[g]..start[g+1]
__global__ void bounds_kernel(const int* __restrict__ batch,
                              int* __restrict__ start, int N_, int G_) {
  int n = blockIdx.x * blockDim.x + threadIdx.x;
  if (n >= N_) return;
  int b = batch[n];
  int bp = (n == 0) ? -1 : batch[n - 1];
  for (int g = bp + 1; g <= b; ++g) start[g] = n;
  if (n == N_ - 1)
    for (int g = b + 1; g <= G_; ++g) start[g] = N_;
}

// ---------------------------------------------------------------------------
// Per-graph softmax-attention pool + output MLP.  One block per graph.
__global__ __launch_bounds__(256) void pool_out_kernel(
    const float* __restrict__ h, const float* __restrict__ score,
    const int* __restrict__ start, const float* __restrict__ W1,
    const float* __restrict__ b1, const float* __restrict__ W2,
    const float* __restrict__ b2, float* __restrict__ out) {
  int g = blockIdx.x;
  int s0 = start[g], s1 = start[g + 1];
  int tid = threadIdx.x;
  __shared__ float red[256];
  __shared__ float pool[64];
  __shared__ float sh_smax, sh_denom;
  float lm = -1e30f;
  for (int n = s0 + tid; n < s1; n += 256) lm = fmaxf(lm, score[n]);
  red[tid] = lm;
  __syncthreads();
  for (int off = 128; off; off >>= 1) {
    if (tid < off) red[tid] = fmaxf(red[tid], red[tid + off]);
    __syncthreads();
  }
  if (tid == 0) sh_smax = red[0];
  __syncthreads();
  float smax = sh_smax;
  __syncthreads();
  float ls = 0.f;
  for (int n = s0 + tid; n < s1; n += 256) ls += __expf(score[n] - smax);
  red[tid] = ls;
  __syncthreads();
  for (int off = 128; off; off >>= 1) {
    if (tid < off) red[tid] += red[tid + off];
    __syncthreads();
  }
  if (tid == 0) sh_denom = red[0];
  __syncthreads();
  float denom = sh_denom;
  float invd = denom > 0.f ? 1.0f / denom : 0.f;
  __syncthreads();
  int f = tid & 63, sub = tid >> 6;
  float acc = 0.f;
  for (int n = s0 + sub; n < s1; n += 4)
    acc = fmaf(__expf(score[n] - smax), h[(size_t)n * 64 + f], acc);
  red[tid] = acc;
  __syncthreads();
  if (tid < 64)
    pool[tid] =
        (red[tid] + red[tid + 64] + red[tid + 128] + red[tid + 192]) * invd;
  __syncthreads();
  if (tid < 64) {
    float a = b1[tid];
#pragma unroll 8
    for (int k = 0; k < 64; ++k) a = fmaf(pool[k], W1[k * 64 + tid], a);
    a = fmaxf(a, 0.f);
    red[tid] = a * W2[tid];
  }
  __syncthreads();
  if (tid == 0) {
    float s = 0.f;
    for (int k = 0; k < 64; ++k) s += red[k];
    out[g] = s + b2[0];
  }
}

// ---------------------------------------------------------------------------
extern "C" void kernel_launch(void* const* d_in, const int* in_sizes, int n_in,
                              void* d_out, int out_size, void* d_ws,
                              size_t ws_size, hipStream_t stream) {
  const float* x          = (const float*)d_in[0];
  const int*   edge_index = (const int*)d_in[1];
  const float* edge_attr  = (const float*)d_in[2];
  const int*   batch_idx  = (const int*)d_in[3];
  const float* gf         = (const float*)d_in[4];
  const float* node_W     = (const float*)d_in[5];
  const float* node_b     = (const float*)d_in[6];
  const float* edge_W     = (const float*)d_in[7];
  const float* edge_b     = (const float*)d_in[8];
  const float* conv_W     = (const float*)d_in[9];
  const float* conv_att   = (const float*)d_in[10];
  const float* conv_b     = (const float*)d_in[11];
  const float* conv_gamma = (const float*)d_in[12];
  const float* conv_beta  = (const float*)d_in[13];
  const float* ga_W1      = (const float*)d_in[14];
  const float* ga_b1      = (const float*)d_in[15];
  const float* ga_W2      = (const float*)d_in[16];
  const float* ga_b2      = (const float*)d_in[17];
  const float* out_W1     = (const float*)d_in[18];
  const float* out_b1     = (const float*)d_in[19];
  const float* out_W2     = (const float*)d_in[20];
  const float* out_b2     = (const float*)d_in[21];
  float* out = (float*)d_out;

  const int N = in_sizes[3];        // 10000
  const int E = in_sizes[2] / 50;   // 40000
  const int G = in_sizes[4] / 108;  // 128
  const int L = 5;

  float* ws = (float*)d_ws;
  float* h    = ws;  ws += (size_t)N * 64;
  float* h0   = ws;  ws += (size_t)N * 64;
  float* ea   = ws;  ws += (size_t)E * 64;
  float* eas  = ws;  ws += (size_t)E * 64;   // row-sorted ea
  float* P    = ws;  ws += (size_t)N * 640;
  float* agg  = ws;  ws += (size_t)N * 64;
  float* scr  = ws;  ws += N;
  int* gstart = (int*)ws;  ws += G + 8;
  int* cnt    = (int*)ws;  ws += N;
  int* cursor = (int*)ws;  ws += N;
  int* rs     = (int*)ws;  ws += E;
  int* cs     = (int*)ws;  ws += E;
  int* es     = (int*)ws;  ws += E;

  const int* row = edge_index;
  const int* col = edge_index + E;

  int nodeBlocks = (N + 3) / 4;
  int edgeBlocks = (E + 3) / 4;
  embed2_kernel<<<nodeBlocks + edgeBlocks, 256, 0, stream>>>(
      x, node_W, node_b, h0, N, edge_attr, edge_W, edge_b, ea, E, nodeBlocks);

  // Edge counting-sort by row (once; reused by all layers).
  (void)hipMemsetAsync(cnt, 0, (size_t)N * sizeof(int), stream);
  count_kernel<<<(E + 255) / 256, 256, 0, stream>>>(row, cnt, E);
  scan_kernel<<<1, 256, 0, stream>>>(cnt, cursor, N);
  scatter_kernel<<<(E + 255) / 256, 256, 0, stream>>>(row, col, cursor, rs, cs,
                                                      es, E);
  gather_ea_kernel<<<(E * 64 + 255) / 256, 256, 0, stream>>>(ea, es, eas, E);
  (void)hipMemsetAsync(agg, 0, (size_t)N * 64 * sizeof(float), stream);

  for (int i = 0; i < L; ++i) {
    const float* Wi = conv_W + (size_t)i * 128 * 640;
    if (i == 0) {
      update_gemm_kernel<<<(N / 4 + 3) / 4, 256, 0, stream>>>(
          h0, h, agg, nullptr, Wi, P, N, -1);
    } else {
      update_gemm_kernel<<<(N / 4 + 3) / 4, 256, 0, stream>>>(
          nullptr, h, agg, conv_b + (i - 1) * 64, Wi, P, N,
          (i - 1) == 0 ? 0 : 1);
    }
    int waves = (E + 7) / 8;
    edge_fused_kernel<<<(waves + 3) / 4, 256, 0, stream>>>(
        P, eas, Wi + 64 * 640, rs, cs, conv_att + (size_t)i * 1280,
        conv_gamma + i * 10, conv_beta + i * 10, agg, E);
  }
  finalize_kernel<<<(N * 64 + 255) / 256, 256, 0, stream>>>(
      h, agg, conv_b + (L - 1) * 64, h0, N * 64);

  score_kernel<<<(N + 3) / 4, 256, 0, stream>>>(h, batch_idx, gf, ga_W1, ga_b1,
                                                ga_W2, ga_b2, scr, N);
  bounds_kernel<<<(N + 255) / 256, 256, 0, stream>>>(batch_idx, gstart, N, G);
  pool_out_kernel<<<G, 256, 0, stream>>>(h, scr, gstart, out_W1, out_b1, out_W2,
                                         out_b2, out);
}